// Round 11
// baseline (219.811 us; speedup 1.0000x reference)
//
#include <hip/hip_runtime.h>
#include <hip/hip_bf16.h>
#include <math.h>

// Problem constants
#define NB     128          // batches
#define SLEN   4096
#define HID_   1024
#define MFULL  32768
#define N_     1024

typedef __bf16 bf16x8 __attribute__((ext_vector_type(8)));
typedef float  f32x4  __attribute__((ext_vector_type(4)));
typedef float  f32x2  __attribute__((ext_vector_type(2)));
typedef __hip_bfloat16 hb;

__device__ __forceinline__ float gelu_tanh(float v) {
    float u = 1.5957691216f * v * (1.0f + 0.044715f * v * v);
    float e = __expf(u);
    float th = (e - 1.0f) / (e + 1.0f);
    return 0.5f * v * (1.0f + th);
}

// ---------------------------------------------------------------- prep ----
// bid <256   : w2t transpose (W2 -> bf16^T)
// bid 256-511: Pb table  Pb[p][c] = sum_k posflat[p*256+k]*W1[16+k][c] + b1[c]
// bid 512-515: SUF table SUF[m][c] = sum_{j>=m} (pos_table[PAD] @ W1j)[c], m=0..16
// bid 516    : scan / rowmap / meta / mc / n_patch output
__global__ __launch_bounds__(256) void prep_all(const float* __restrict__ W1,
                                                const float* __restrict__ b1,
                                                const float* __restrict__ W2,
                                                const float* __restrict__ pos_table,
                                                const int* __restrict__ lengths,
                                                hb* __restrict__ w2t,
                                                float* __restrict__ Pb,
                                                float* __restrict__ SUF,
                                                unsigned short* __restrict__ rowmap,
                                                int* __restrict__ meta,
                                                float* __restrict__ np_out) {
    const int bid = blockIdx.x;
    const int t = threadIdx.x;

    if (bid < 256) {                       // ---- w2t transpose
        __shared__ float tt[64][65];
        const int kt = bid >> 4, nt = bid & 15;
        const int c = t & 63, r4 = t >> 6;
#pragma unroll
        for (int j = 0; j < 16; ++j) {
            int r = j * 4 + r4;
            tt[r][c] = W2[(kt * 64 + r) * 1024 + nt * 64 + c];
        }
        __syncthreads();
#pragma unroll
        for (int j = 0; j < 16; ++j) {
            int r = j * 4 + r4;
            w2t[(nt * 64 + r) * 1024 + kt * 64 + c] = __float2bfloat16(tt[c][r]);
        }
    } else if (bid < 512) {                // ---- Pb GEMM (8p x 128c per block)
        __shared__ float pl[8 * 256];
        const int id = bid - 256;
        const int pg = id >> 3;            // 0..31
        const int cgb = (id & 7) * 128;    // col base
#pragma unroll
        for (int i = 0; i < 8; ++i) {
            int idx = t + i * 256;
            pl[idx] = pos_table[pg * 8 * 256 + idx];   // posflat contiguous
        }
        __syncthreads();
        const int prow = t >> 5;
        const int c0 = cgb + (t & 31) * 4;
        f32x4 acc = *(const f32x4*)&b1[c0];
        const float* pr = &pl[prow * 256];
#pragma unroll 4
        for (int k = 0; k < 256; ++k)
            acc += pr[k] * *(const f32x4*)&W1[(16 + k) * 1024 + c0];
        *(f32x4*)&Pb[(pg * 8 + prow) * 1024 + c0] = acc;
    } else if (bid < 516) {                // ---- SUF table
        const int c = (bid - 512) * 256 + t;
        float padv[16];
#pragma unroll
        for (int e = 0; e < 16; ++e) padv[e] = pos_table[4096 * 16 + e];
        float tmp[16];
#pragma unroll
        for (int j = 0; j < 16; ++j) {
            float s = 0.0f;
#pragma unroll
            for (int e = 0; e < 16; ++e)
                s += padv[e] * W1[(16 + 16 * j + e) * 1024 + c];
            tmp[j] = s;
        }
        float run = 0.0f;
        SUF[16 * 1024 + c] = 0.0f;
        for (int m = 15; m >= 0; --m) {
            run += tmp[m];
            SUF[m * 1024 + c] = run;
        }
    } else {                               // ---- scan / rowmap / meta
        __shared__ int sc[NB], sNp[NB];
        if (t < NB) { sNp[t] = (lengths[t] + 15) >> 4; sc[t] = sNp[t]; }
        __syncthreads();
        for (int d = 1; d < NB; d <<= 1) {
            int v = 0;
            if (t < NB && t >= d) v = sc[t - d];
            __syncthreads();
            if (t < NB && t >= d) sc[t] += v;
            __syncthreads();
        }
        if (t < NB) {
            meta[t] = sc[t] - sNp[t];      // exclusive offset
            np_out[t] = (float)sNp[t];
        }
        if (t == 0) meta[NB] = sc[NB - 1]; // Mc
        __syncthreads();
        for (int b = 0; b < NB; ++b) {
            const int off = sc[b] - sNp[b], np = sNp[b];
            for (int p = t; p < np; p += 256)
                rowmap[off + p] = (unsigned short)(b * 256 + p);
        }
    }
}

// ---------------------------------------------------------------- h ----
// h[row] = gelu( vals@W1[:16] + Pb[p] )  for compact rows (boundary rows fixed later)
// + fused zero-fill of invalid out rows.
__global__ __launch_bounds__(512) void build_h(const float* __restrict__ x,
                                               const int* __restrict__ lengths,
                                               const float* __restrict__ W1,
                                               const float* __restrict__ Pb,
                                               const unsigned short* __restrict__ rowmap,
                                               const int* __restrict__ meta,
                                               hb* __restrict__ h,
                                               float* __restrict__ out) {
    const int bid = blockIdx.x;            // 0..2047
    const int t = threadIdx.x;

    // zero-fill slice: rows r with p >= n_patch(b)
    for (int r = bid; r < MFULL; r += 2048) {
        const int b = r >> 8, p = r & 255;
        const int np = (lengths[b] + 15) >> 4;
        if (p >= np)
            *(f32x2*)(out + (long)r * N_ + t * 2) = (f32x2)0.0f;
    }

    const int Mc = meta[NB];
    const int gr0 = bid * 16;
    if (gr0 >= Mc) return;

    __shared__ float vals[16][16];
    __shared__ int rinfo[16];
    if (t < 16) rinfo[t] = (gr0 + t < Mc) ? (int)rowmap[gr0 + t] : -1;
    __syncthreads();
    if (t < 256) {
        const int row = t >> 4, j = t & 15;
        const int ri = rinfo[row];
        if (ri >= 0) {
            const int b = ri >> 8, p = ri & 255;
            const int L = lengths[b];
            const int tt = p * 16 + j;
            const int idx = (tt < L) ? tt : (L - 1);
            vals[row][j] = x[((long)b * SLEN + idx) * 2];
        }
    }
    __syncthreads();

    const int row = t >> 5, cg = t & 31;
    const int ri = rinfo[row];
    if (ri < 0) return;
    const int p = ri & 255;

    f32x4 a[4][2];
#pragma unroll
    for (int i = 0; i < 4; ++i) {
        const int c0 = i * 256 + cg * 8;
        a[i][0] = *(const f32x4*)&Pb[p * 1024 + c0];
        a[i][1] = *(const f32x4*)&Pb[p * 1024 + c0 + 4];
    }
#pragma unroll
    for (int j = 0; j < 16; ++j) {
        const float s = vals[row][j];
        const float* wj = &W1[j * 1024];
#pragma unroll
        for (int i = 0; i < 4; ++i) {
            const int c0 = i * 256 + cg * 8;
            a[i][0] += s * *(const f32x4*)&wj[c0];
            a[i][1] += s * *(const f32x4*)&wj[c0 + 4];
        }
    }
    hb* hr = h + (long)(gr0 + row) * 1024;
#pragma unroll
    for (int i = 0; i < 4; ++i) {
        bf16x8 o;
#pragma unroll
        for (int e = 0; e < 4; ++e) o[e] = (__bf16)gelu_tanh(a[i][0][e]);
#pragma unroll
        for (int e = 0; e < 4; ++e) o[4 + e] = (__bf16)gelu_tanh(a[i][1][e]);
        *(bf16x8*)(hr + i * 256 + cg * 8) = o;
    }
}

// boundary rows (one per batch): exact 272-dot with PAD-mixed positions
__global__ __launch_bounds__(256) void boundary_h(const float* __restrict__ x,
                                                  const int* __restrict__ lengths,
                                                  const float* __restrict__ W1,
                                                  const float* __restrict__ b1,
                                                  const float* __restrict__ pos_table,
                                                  const float* __restrict__ SUF,
                                                  const int* __restrict__ meta,
                                                  hb* __restrict__ h) {
    const int b = blockIdx.x;
    const int t = threadIdx.x;
    const int L = lengths[b];
    const int np = (L + 15) >> 4;
    const int p = np - 1;
    const int m = L - p * 16;              // 1..16
    const long gr = meta[b] + p;
    const int c0 = t * 4;

    f32x4 acc = *(const f32x4*)&SUF[m * 1024 + c0];
    acc += *(const f32x4*)&b1[c0];
#pragma unroll
    for (int j = 0; j < 16; ++j) {
        const int tt = p * 16 + j;
        const int idx = (tt < L) ? tt : (L - 1);
        const float v = x[((long)b * SLEN + idx) * 2];
        acc += v * *(const f32x4*)&W1[j * 1024 + c0];
    }
    const int km = m * 16;
    const float* pf = pos_table + p * 256;  // posflat, contiguous
    for (int k = 0; k < km; ++k)
        acc += pf[k] * *(const f32x4*)&W1[(16 + k) * 1024 + c0];

    hb* hr = h + gr * 1024 + c0;
#pragma unroll
    for (int e = 0; e < 4; ++e) hr[e] = __float2bfloat16(gelu_tanh(acc[e]));
}

// ---------------------------------------------------------------- GEMM ----

__device__ __forceinline__ void gl_lds16(const hb* g, hb* l) {
    __builtin_amdgcn_global_load_lds(
        (const __attribute__((address_space(1))) unsigned int*)g,
        (__attribute__((address_space(3))) unsigned int*)l, 16, 0, 0);
}

// out[rowmap[r]] = f32(h_c @ w2t^T + b2), 256x256 tile, BK=64, 8 waves,
// double-buffered LDS, gray quadrants, reg-held B, counted vmcnt(8) (R5-proven).
__global__ __launch_bounds__(512, 2) void gemm_out(const hb* __restrict__ A,
                                                   const hb* __restrict__ BT,
                                                   const float* __restrict__ bias,
                                                   const unsigned short* __restrict__ rowmap,
                                                   const int* __restrict__ meta,
                                                   float* __restrict__ FOut) {
    __shared__ __align__(16) hb Sh[4][16384];   // 128 KiB
    const int K = 1024, nt = 16;

    const int Mc = meta[NB];
    const int activeBm = (Mc + 255) >> 8;
    const int nActive = activeBm * 4;
    const int bid = blockIdx.x;
    if (bid >= nActive) return;
    const int q = nActive >> 3, r = nActive & 7;
    const int xcd = bid & 7, idx = bid >> 3;
    const int wg = (xcd < r ? xcd * (q + 1) : r * (q + 1) + (xcd - r) * q) + idx;
    const int bm = wg >> 2;
    const int bn = wg & 3;

    const int tid = threadIdx.x;
    const int wid = tid >> 6, lane = tid & 63;
    const int wr = wid >> 2, wc = wid & 3;
    const int fr = lane & 15, kg = lane >> 4;
    const int swz = (fr & 7) << 4;

    const long arow0 = (long)bm * 256;
    const int  brow0 = bn * 256;
    const hb* Bbase = BT + (long)brow0 * K;

    const int srow = tid >> 3;
    const int sel  = (((tid & 7) << 4) ^ ((srow & 7) << 4)) >> 1;
    const int ldst = tid * 8;

    f32x4 acc[8][4] = {};

    auto stage = [&](int t, int bsel) {
        const int k0 = t << 6;
#pragma unroll
        for (int j = 0; j < 4; ++j) {
            long gr = arow0 + j * 64 + srow;
            if (gr >= Mc) gr = Mc - 1;
            gl_lds16(A + gr * K + k0 + sel, &Sh[bsel][j * 4096 + ldst]);
        }
#pragma unroll
        for (int j = 0; j < 4; ++j)
            gl_lds16(Bbase + (long)(j * 64 + srow) * K + k0 + sel,
                     &Sh[2 + bsel][j * 4096 + ldst]);
    };

    stage(0, 0);
    stage(1, 1);
    asm volatile("s_waitcnt vmcnt(8)" ::: "memory");
    asm volatile("s_barrier" ::: "memory");

#define LDA_(dst, Ab, half)                                                  \
    _Pragma("unroll") for (int i = 0; i < 4; ++i)                            \
    _Pragma("unroll") for (int ks = 0; ks < 2; ++ks)                         \
        dst[i][ks] = *(const bf16x8*)((Ab) +                                 \
            (wr * 128 + (half) * 64 + i * 16 + fr) * 128 +                   \
            ((ks * 64 + kg * 16) ^ swz));

#define LDB_(Bb, half)                                                       \
    _Pragma("unroll") for (int jn = 0; jn < 2; ++jn)                         \
    _Pragma("unroll") for (int ks = 0; ks < 2; ++ks)                         \
        Bf[half][jn][ks] = *(const bf16x8*)((Bb) +                           \
            (wc * 64 + (half) * 32 + jn * 16 + fr) * 128 +                   \
            ((ks * 64 + kg * 16) ^ swz));

#define MFMA_QUAD(Aarr, a, b)                                                \
    __builtin_amdgcn_s_setprio(1);                                           \
    _Pragma("unroll") for (int ks = 0; ks < 2; ++ks)                         \
    _Pragma("unroll") for (int i = 0; i < 4; ++i)                            \
    _Pragma("unroll") for (int jn = 0; jn < 2; ++jn)                         \
        acc[(a) * 4 + i][(b) * 2 + jn] =                                     \
            __builtin_amdgcn_mfma_f32_16x16x32_bf16(                         \
                Aarr[i][ks], Bf[b][jn][ks], acc[(a) * 4 + i][(b) * 2 + jn],  \
                0, 0, 0);                                                    \
    __builtin_amdgcn_s_setprio(0);

    for (int t = 0; t < nt; ++t) {
        const char* Ab = (const char*)(&Sh[t & 1][0]);
        const char* Bb = (const char*)(&Sh[2 + (t & 1)][0]);
        bf16x8 A0[4][2], A1[4][2], Bf[2][2][2];

        LDB_(Bb, 0)
        LDA_(A0, Ab, 0)
        MFMA_QUAD(A0, 0, 0)
        LDB_(Bb, 1)
        MFMA_QUAD(A0, 0, 1)
        LDA_(A1, Ab, 1)
        MFMA_QUAD(A1, 1, 1)
        asm volatile("s_waitcnt lgkmcnt(0)" ::: "memory");
        asm volatile("s_barrier" ::: "memory");
        if (t + 2 < nt) stage(t + 2, t & 1);
        MFMA_QUAD(A1, 1, 0)
        if (t + 1 < nt) {
            if (t + 2 < nt) {
                asm volatile("s_waitcnt vmcnt(8)" ::: "memory");
            } else {
                asm volatile("s_waitcnt vmcnt(0)" ::: "memory");
            }
            asm volatile("s_barrier" ::: "memory");
        }
    }

    const int rbase = wr * 128 + kg * 4;
    const int cbase = wc * 64 + fr;
    float bvv[4];
#pragma unroll
    for (int ni = 0; ni < 4; ++ni) bvv[ni] = bias[bn * 256 + cbase + ni * 16];

    float* Cf = (float*)Sh;
#pragma unroll
    for (int half = 0; half < 2; ++half) {
        if (half) __syncthreads();
        if ((wc >> 1) == half) {
#pragma unroll
            for (int ni = 0; ni < 4; ++ni) {
                const int col = cbase + ni * 16 - half * 128;
#pragma unroll
                for (int mi = 0; mi < 8; ++mi)
#pragma unroll
                    for (int r2 = 0; r2 < 4; ++r2)
                        Cf[(rbase + mi * 16 + r2) * 128 + col] =
                            acc[mi][ni][r2] + bvv[ni];
            }
        }
        __syncthreads();
#pragma unroll
        for (int c = 0; c < 16; ++c) {
            const int e = (c * 512 + tid) * 4;
            const int row = e >> 7, col = e & 127;
            const long cidx = arow0 + row;
            if (cidx < Mc) {
                f32x4 v = *(const f32x4*)(Cf + e);
                *(f32x4*)(FOut + (long)rowmap[cidx] * N_ + bn * 256 + half * 128 + col) = v;
            }
        }
    }
}

// -------------------------------------------------------------- launch ----

extern "C" void kernel_launch(void* const* d_in, const int* in_sizes, int n_in,
                              void* d_out, int out_size, void* d_ws, size_t ws_size,
                              hipStream_t stream) {
    const float* x         = (const float*)d_in[0];
    const int*   lengths   = (const int*)d_in[1];
    const float* pos_table = (const float*)d_in[2];
    const float* W1        = (const float*)d_in[3];
    const float* b1        = (const float*)d_in[4];
    const float* W2        = (const float*)d_in[5];
    const float* b2        = (const float*)d_in[6];
    float* out = (float*)d_out;

    char* ws = (char*)d_ws;
    hb* w2t                = (hb*)(ws);                        //  2,097,152 B
    hb* h                  = (hb*)(ws + 2097152);              // 67,108,864 B
    float* Pb              = (float*)(ws + 69206016);          //  1,048,576 B
    float* SUF             = (float*)(ws + 70254592);          //     69,632 B
    unsigned short* rowmap = (unsigned short*)(ws + 70324224); //     65,536 B
    int* meta              = (int*)(ws + 70389760);            //        516 B

    hipLaunchKernelGGL(prep_all, dim3(517), dim3(256), 0, stream,
                       W1, b1, W2, pos_table, lengths, w2t, Pb, SUF, rowmap, meta,
                       out + (long)MFULL * N_);
    hipLaunchKernelGGL(build_h, dim3(2048), dim3(512), 0, stream,
                       x, lengths, W1, Pb, rowmap, meta, h, out);
    hipLaunchKernelGGL(boundary_h, dim3(NB), dim3(256), 0, stream,
                       x, lengths, W1, b1, pos_table, SUF, meta, h);
    hipLaunchKernelGGL(gemm_out, dim3(512), dim3(512), 0, stream,
                       h, w2t, b2, rowmap, meta, out);
}

// Round 12
// 191.501 us; speedup vs baseline: 1.1478x; 1.1478x over previous
//
#include <hip/hip_runtime.h>
#include <hip/hip_bf16.h>
#include <math.h>

// Problem constants
#define NB     128          // batches
#define SLEN   4096
#define HID_   1024
#define MFULL  32768
#define N_     1024

typedef __bf16 bf16x8 __attribute__((ext_vector_type(8)));
typedef float  f32x4  __attribute__((ext_vector_type(4)));
typedef __hip_bfloat16 hb;

__device__ __forceinline__ float gelu_tanh(float v) {
    float u = 1.5957691216f * v * (1.0f + 0.044715f * v * v);
    float e = __expf(u);
    float th = (e - 1.0f) / (e + 1.0f);
    return 0.5f * v * (1.0f + th);
}

// ---------------------------------------------------------------- prep ----
// bid <256   : w2t transpose (W2 -> bf16^T)
// bid 256-511: Pb table  Pb[p][c] = sum_k posflat[p*256+k]*W1[16+k][c] + b1[c]
// bid 512-515: SUF table SUF[m][c] = sum_{j>=m} (pos_table[PAD] @ W1j)[c], m=0..16
// bid 516    : scan / rowmap / meta / Mc / n_patch output
__global__ __launch_bounds__(256) void prep_all(const float* __restrict__ W1,
                                                const float* __restrict__ b1,
                                                const float* __restrict__ W2,
                                                const float* __restrict__ pos_table,
                                                const int* __restrict__ lengths,
                                                hb* __restrict__ w2t,
                                                float* __restrict__ Pb,
                                                float* __restrict__ SUF,
                                                unsigned short* __restrict__ rowmap,
                                                int* __restrict__ meta,
                                                float* __restrict__ np_out) {
    const int bid = blockIdx.x;
    const int t = threadIdx.x;

    if (bid < 256) {                       // ---- w2t transpose
        __shared__ float tt[64][65];
        const int kt = bid >> 4, nt = bid & 15;
        const int c = t & 63, r4 = t >> 6;
#pragma unroll
        for (int j = 0; j < 16; ++j) {
            int r = j * 4 + r4;
            tt[r][c] = W2[(kt * 64 + r) * 1024 + nt * 64 + c];
        }
        __syncthreads();
#pragma unroll
        for (int j = 0; j < 16; ++j) {
            int r = j * 4 + r4;
            w2t[(nt * 64 + r) * 1024 + kt * 64 + c] = __float2bfloat16(tt[c][r]);
        }
    } else if (bid < 512) {                // ---- Pb GEMM (8p x 128c per block)
        __shared__ float pl[8 * 256];
        const int id = bid - 256;
        const int pg = id >> 3;            // 0..31
        const int cgb = (id & 7) * 128;    // col base
#pragma unroll
        for (int i = 0; i < 8; ++i) {
            int idx = t + i * 256;
            pl[idx] = pos_table[pg * 8 * 256 + idx];   // posflat contiguous
        }
        __syncthreads();
        const int prow = t >> 5;
        const int c0 = cgb + (t & 31) * 4;
        f32x4 acc = *(const f32x4*)&b1[c0];
        const float* pr = &pl[prow * 256];
#pragma unroll 4
        for (int k = 0; k < 256; ++k)
            acc += pr[k] * *(const f32x4*)&W1[(16 + k) * 1024 + c0];
        *(f32x4*)&Pb[(pg * 8 + prow) * 1024 + c0] = acc;
    } else if (bid < 516) {                // ---- SUF table
        const int c = (bid - 512) * 256 + t;
        float padv[16];
#pragma unroll
        for (int e = 0; e < 16; ++e) padv[e] = pos_table[4096 * 16 + e];
        float tmp[16];
#pragma unroll
        for (int j = 0; j < 16; ++j) {
            float s = 0.0f;
#pragma unroll
            for (int e = 0; e < 16; ++e)
                s += padv[e] * W1[(16 + 16 * j + e) * 1024 + c];
            tmp[j] = s;
        }
        float run = 0.0f;
        SUF[16 * 1024 + c] = 0.0f;
        for (int m = 15; m >= 0; --m) {
            run += tmp[m];
            SUF[m * 1024 + c] = run;
        }
    } else {                               // ---- scan / rowmap / meta
        __shared__ int sc[NB], sNp[NB];
        if (t < NB) { sNp[t] = (lengths[t] + 15) >> 4; sc[t] = sNp[t]; }
        __syncthreads();
        for (int d = 1; d < NB; d <<= 1) {
            int v = 0;
            if (t < NB && t >= d) v = sc[t - d];
            __syncthreads();
            if (t < NB && t >= d) sc[t] += v;
            __syncthreads();
        }
        if (t < NB) {
            meta[t] = sc[t] - sNp[t];      // exclusive offset
            np_out[t] = (float)sNp[t];
        }
        if (t == 0) meta[NB] = sc[NB - 1]; // Mc
        __syncthreads();
        for (int b = 0; b < NB; ++b) {
            const int off = sc[b] - sNp[b], np = sNp[b];
            for (int p = t; p < np; p += 256)
                rowmap[off + p] = (unsigned short)(b * 256 + p);
        }
    }
}

// ---------------------------------------------------------------- h ----
// h[row] = gelu( vals@W1[:16] + Pb[p] )  for compact rows (boundary rows fixed later)
__global__ __launch_bounds__(512) void build_h(const float* __restrict__ x,
                                               const int* __restrict__ lengths,
                                               const float* __restrict__ W1,
                                               const float* __restrict__ Pb,
                                               const unsigned short* __restrict__ rowmap,
                                               const int* __restrict__ meta,
                                               hb* __restrict__ h) {
    const int bid = blockIdx.x;            // 0..2047
    const int t = threadIdx.x;

    const int Mc = meta[NB];
    const int gr0 = bid * 16;
    if (gr0 >= Mc) return;

    __shared__ float vals[16][16];
    __shared__ int rinfo[16];
    if (t < 16) rinfo[t] = (gr0 + t < Mc) ? (int)rowmap[gr0 + t] : -1;
    __syncthreads();
    if (t < 256) {
        const int row = t >> 4, j = t & 15;
        const int ri = rinfo[row];
        if (ri >= 0) {
            const int b = ri >> 8, p = ri & 255;
            const int L = lengths[b];
            const int tt = p * 16 + j;
            const int idx = (tt < L) ? tt : (L - 1);
            vals[row][j] = x[((long)b * SLEN + idx) * 2];
        }
    }
    __syncthreads();

    const int row = t >> 5, cg = t & 31;
    const int ri = rinfo[row];
    if (ri < 0) return;
    const int p = ri & 255;

    f32x4 a[4][2];
#pragma unroll
    for (int i = 0; i < 4; ++i) {
        const int c0 = i * 256 + cg * 8;
        a[i][0] = *(const f32x4*)&Pb[p * 1024 + c0];
        a[i][1] = *(const f32x4*)&Pb[p * 1024 + c0 + 4];
    }
#pragma unroll
    for (int j = 0; j < 16; ++j) {
        const float s = vals[row][j];
        const float* wj = &W1[j * 1024];
#pragma unroll
        for (int i = 0; i < 4; ++i) {
            const int c0 = i * 256 + cg * 8;
            a[i][0] += s * *(const f32x4*)&wj[c0];
            a[i][1] += s * *(const f32x4*)&wj[c0 + 4];
        }
    }
    hb* hr = h + (long)(gr0 + row) * 1024;
#pragma unroll
    for (int i = 0; i < 4; ++i) {
        bf16x8 o;
#pragma unroll
        for (int e = 0; e < 4; ++e) o[e] = (__bf16)gelu_tanh(a[i][0][e]);
#pragma unroll
        for (int e = 0; e < 4; ++e) o[4 + e] = (__bf16)gelu_tanh(a[i][1][e]);
        *(bf16x8*)(hr + i * 256 + cg * 8) = o;
    }
}

// boundary rows (one per batch): exact 272-dot with PAD-mixed positions
__global__ __launch_bounds__(256) void boundary_h(const float* __restrict__ x,
                                                  const int* __restrict__ lengths,
                                                  const float* __restrict__ W1,
                                                  const float* __restrict__ b1,
                                                  const float* __restrict__ pos_table,
                                                  const float* __restrict__ SUF,
                                                  const int* __restrict__ meta,
                                                  hb* __restrict__ h) {
    const int b = blockIdx.x;
    const int t = threadIdx.x;
    const int L = lengths[b];
    const int np = (L + 15) >> 4;
    const int p = np - 1;
    const int m = L - p * 16;              // 1..16
    const long gr = meta[b] + p;
    const int c0 = t * 4;

    f32x4 acc = *(const f32x4*)&SUF[m * 1024 + c0];
    acc += *(const f32x4*)&b1[c0];
#pragma unroll
    for (int j = 0; j < 16; ++j) {
        const int tt = p * 16 + j;
        const int idx = (tt < L) ? tt : (L - 1);
        const float v = x[((long)b * SLEN + idx) * 2];
        acc += v * *(const f32x4*)&W1[j * 1024 + c0];
    }
    const int km = m * 16;
    const float* pf = pos_table + p * 256;  // posflat, contiguous
#pragma unroll 4
    for (int k = 0; k < km; ++k)
        acc += pf[k] * *(const f32x4*)&W1[(16 + k) * 1024 + c0];

    hb* hr = h + gr * 1024 + c0;
#pragma unroll
    for (int e = 0; e < 4; ++e) hr[e] = __float2bfloat16(gelu_tanh(acc[e]));
}

// zero all out rows with p >= n_patch(b) — balanced grid-stride (R7-proven)
__global__ __launch_bounds__(256) void zero_fill(const int* __restrict__ lengths,
                                                 float* __restrict__ out) {
    for (int r = blockIdx.x; r < MFULL; r += 512) {
        const int b = r >> 8, p = r & 255;
        const int np = (lengths[b] + 15) >> 4;
        if (p >= np)
            *(f32x4*)(out + (long)r * N_ + threadIdx.x * 4) = (f32x4)0.0f;
    }
}

// ---------------------------------------------------------------- GEMM ----

__device__ __forceinline__ void gl_lds16(const hb* g, hb* l) {
    __builtin_amdgcn_global_load_lds(
        (const __attribute__((address_space(1))) unsigned int*)g,
        (__attribute__((address_space(3))) unsigned int*)l, 16, 0, 0);
}

// out[rowmap[r]] = f32(h_c @ w2t^T + b2), 256x256 tile, BK=64, 8 waves,
// double-buffered LDS, gray quadrants, reg-held B, counted vmcnt(8) (R5-proven).
// K, nt are RUNTIME args (anti-constant-fold: keeps the K-loop rolled, I-cache-resident).
__global__ __launch_bounds__(512, 2) void gemm_out(const hb* __restrict__ A,
                                                   const hb* __restrict__ BT,
                                                   const float* __restrict__ bias,
                                                   const unsigned short* __restrict__ rowmap,
                                                   const int* __restrict__ meta,
                                                   float* __restrict__ FOut,
                                                   int K, int nt) {
    __shared__ __align__(16) hb Sh[4][16384];   // 128 KiB

    const int Mc = meta[NB];
    const int activeBm = (Mc + 255) >> 8;
    const int nActive = activeBm * 4;
    const int bid = blockIdx.x;
    if (bid >= nActive) return;
    const int q = nActive >> 3, r = nActive & 7;
    const int xcd = bid & 7, idx = bid >> 3;
    const int wg = (xcd < r ? xcd * (q + 1) : r * (q + 1) + (xcd - r) * q) + idx;
    const int bm = wg >> 2;
    const int bn = wg & 3;

    const int tid = threadIdx.x;
    const int wid = tid >> 6, lane = tid & 63;
    const int wr = wid >> 2, wc = wid & 3;
    const int fr = lane & 15, kg = lane >> 4;
    const int swz = (fr & 7) << 4;

    const long arow0 = (long)bm * 256;
    const int  brow0 = bn * 256;
    const hb* Bbase = BT + (long)brow0 * K;

    const int srow = tid >> 3;
    const int sel  = (((tid & 7) << 4) ^ ((srow & 7) << 4)) >> 1;
    const int ldst = tid * 8;

    f32x4 acc[8][4] = {};

    auto stage = [&](int t, int bsel) {
        const int k0 = t << 6;
#pragma unroll
        for (int j = 0; j < 4; ++j) {
            long gr = arow0 + j * 64 + srow;
            if (gr >= Mc) gr = Mc - 1;
            gl_lds16(A + gr * K + k0 + sel, &Sh[bsel][j * 4096 + ldst]);
        }
#pragma unroll
        for (int j = 0; j < 4; ++j)
            gl_lds16(Bbase + (long)(j * 64 + srow) * K + k0 + sel,
                     &Sh[2 + bsel][j * 4096 + ldst]);
    };

    stage(0, 0);
    stage(1, 1);
    asm volatile("s_waitcnt vmcnt(8)" ::: "memory");
    asm volatile("s_barrier" ::: "memory");

#define LDA_(dst, Ab, half)                                                  \
    _Pragma("unroll") for (int i = 0; i < 4; ++i)                            \
    _Pragma("unroll") for (int ks = 0; ks < 2; ++ks)                         \
        dst[i][ks] = *(const bf16x8*)((Ab) +                                 \
            (wr * 128 + (half) * 64 + i * 16 + fr) * 128 +                   \
            ((ks * 64 + kg * 16) ^ swz));

#define LDB_(Bb, half)                                                       \
    _Pragma("unroll") for (int jn = 0; jn < 2; ++jn)                         \
    _Pragma("unroll") for (int ks = 0; ks < 2; ++ks)                         \
        Bf[half][jn][ks] = *(const bf16x8*)((Bb) +                           \
            (wc * 64 + (half) * 32 + jn * 16 + fr) * 128 +                   \
            ((ks * 64 + kg * 16) ^ swz));

#define MFMA_QUAD(Aarr, a, b)                                                \
    __builtin_amdgcn_s_setprio(1);                                           \
    _Pragma("unroll") for (int ks = 0; ks < 2; ++ks)                         \
    _Pragma("unroll") for (int i = 0; i < 4; ++i)                            \
    _Pragma("unroll") for (int jn = 0; jn < 2; ++jn)                         \
        acc[(a) * 4 + i][(b) * 2 + jn] =                                     \
            __builtin_amdgcn_mfma_f32_16x16x32_bf16(                         \
                Aarr[i][ks], Bf[b][jn][ks], acc[(a) * 4 + i][(b) * 2 + jn],  \
                0, 0, 0);                                                    \
    __builtin_amdgcn_s_setprio(0);

    for (int t = 0; t < nt; ++t) {
        const char* Ab = (const char*)(&Sh[t & 1][0]);
        const char* Bb = (const char*)(&Sh[2 + (t & 1)][0]);
        bf16x8 A0[4][2], A1[4][2], Bf[2][2][2];

        LDB_(Bb, 0)
        LDA_(A0, Ab, 0)
        MFMA_QUAD(A0, 0, 0)
        LDB_(Bb, 1)
        MFMA_QUAD(A0, 0, 1)
        LDA_(A1, Ab, 1)
        MFMA_QUAD(A1, 1, 1)
        asm volatile("s_waitcnt lgkmcnt(0)" ::: "memory");
        asm volatile("s_barrier" ::: "memory");
        if (t + 2 < nt) stage(t + 2, t & 1);
        MFMA_QUAD(A1, 1, 0)
        if (t + 1 < nt) {
            if (t + 2 < nt) {
                asm volatile("s_waitcnt vmcnt(8)" ::: "memory");
            } else {
                asm volatile("s_waitcnt vmcnt(0)" ::: "memory");
            }
            asm volatile("s_barrier" ::: "memory");
        }
    }

    const int rbase = wr * 128 + kg * 4;
    const int cbase = wc * 64 + fr;
    float bvv[4];
#pragma unroll
    for (int ni = 0; ni < 4; ++ni) bvv[ni] = bias[bn * 256 + cbase + ni * 16];

    float* Cf = (float*)Sh;
#pragma unroll
    for (int half = 0; half < 2; ++half) {
        if (half) __syncthreads();
        if ((wc >> 1) == half) {
#pragma unroll
            for (int ni = 0; ni < 4; ++ni) {
                const int col = cbase + ni * 16 - half * 128;
#pragma unroll
                for (int mi = 0; mi < 8; ++mi)
#pragma unroll
                    for (int r2 = 0; r2 < 4; ++r2)
                        Cf[(rbase + mi * 16 + r2) * 128 + col] =
                            acc[mi][ni][r2] + bvv[ni];
            }
        }
        __syncthreads();
#pragma unroll
        for (int c = 0; c < 16; ++c) {
            const int e = (c * 512 + tid) * 4;
            const int row = e >> 7, col = e & 127;
            const long cidx = arow0 + row;
            if (cidx < Mc) {
                f32x4 v = *(const f32x4*)(Cf + e);
                *(f32x4*)(FOut + (long)rowmap[cidx] * N_ + bn * 256 + half * 128 + col) = v;
            }
        }
    }
}

// -------------------------------------------------------------- launch ----

extern "C" void kernel_launch(void* const* d_in, const int* in_sizes, int n_in,
                              void* d_out, int out_size, void* d_ws, size_t ws_size,
                              hipStream_t stream) {
    const float* x         = (const float*)d_in[0];
    const int*   lengths   = (const int*)d_in[1];
    const float* pos_table = (const float*)d_in[2];
    const float* W1        = (const float*)d_in[3];
    const float* b1        = (const float*)d_in[4];
    const float* W2        = (const float*)d_in[5];
    const float* b2        = (const float*)d_in[6];
    float* out = (float*)d_out;

    char* ws = (char*)d_ws;
    hb* w2t                = (hb*)(ws);                        //  2,097,152 B
    hb* h                  = (hb*)(ws + 2097152);              // 67,108,864 B
    float* Pb              = (float*)(ws + 69206016);          //  1,048,576 B
    float* SUF             = (float*)(ws + 70254592);          //     69,632 B
    unsigned short* rowmap = (unsigned short*)(ws + 70324224); //     65,536 B
    int* meta              = (int*)(ws + 70389760);            //        516 B

    hipLaunchKernelGGL(prep_all, dim3(517), dim3(256), 0, stream,
                       W1, b1, W2, pos_table, lengths, w2t, Pb, SUF, rowmap, meta,
                       out + (long)MFULL * N_);
    hipLaunchKernelGGL(build_h, dim3(2048), dim3(512), 0, stream,
                       x, lengths, W1, Pb, rowmap, meta, h);
    hipLaunchKernelGGL(boundary_h, dim3(NB), dim3(256), 0, stream,
                       x, lengths, W1, b1, pos_table, SUF, meta, h);
    hipLaunchKernelGGL(zero_fill, dim3(512), dim3(256), 0, stream, lengths, out);
    hipLaunchKernelGGL(gemm_out, dim3(512), dim3(512), 0, stream,
                       h, w2t, b2, rowmap, meta, out, 1024, 16);
}

// Round 13
// 173.528 us; speedup vs baseline: 1.2667x; 1.1036x over previous
//
#include <hip/hip_runtime.h>
#include <hip/hip_bf16.h>
#include <math.h>

// Problem constants
#define NB     128          // batches
#define SLEN   4096
#define HID_   1024
#define MFULL  32768
#define N_     1024

typedef __bf16 bf16x8 __attribute__((ext_vector_type(8)));
typedef float  f32x4  __attribute__((ext_vector_type(4)));
typedef __hip_bfloat16 hb;

__device__ __forceinline__ float gelu_tanh(float v) {
    float u = 1.5957691216f * v * (1.0f + 0.044715f * v * v);
    float e = __expf(u);
    float th = (e - 1.0f) / (e + 1.0f);
    return 0.5f * v * (1.0f + th);
}

// ---------------------------------------------------------------- prep ----
// bid <256   : w2t transpose (W2 -> bf16^T)
// bid 256-511: Pb table  Pb[p][c] = sum_k posflat[p*256+k]*W1[16+k][c] + b1[c]
// bid 512-515: SUF table SUF[m][c] = sum over full-PAD 16-blocks j>=... (see R12)
// bid 516    : scan / rowmap / meta / Mc / n_patch output
__global__ __launch_bounds__(256) void prep_all(const float* __restrict__ W1,
                                                const float* __restrict__ b1,
                                                const float* __restrict__ W2,
                                                const float* __restrict__ pos_table,
                                                const int* __restrict__ lengths,
                                                hb* __restrict__ w2t,
                                                float* __restrict__ Pb,
                                                float* __restrict__ SUF,
                                                unsigned short* __restrict__ rowmap,
                                                int* __restrict__ meta,
                                                float* __restrict__ np_out) {
    const int bid = blockIdx.x;
    const int t = threadIdx.x;

    if (bid < 256) {                       // ---- w2t transpose
        __shared__ float tt[64][65];
        const int kt = bid >> 4, nt = bid & 15;
        const int c = t & 63, r4 = t >> 6;
#pragma unroll
        for (int j = 0; j < 16; ++j) {
            int r = j * 4 + r4;
            tt[r][c] = W2[(kt * 64 + r) * 1024 + nt * 64 + c];
        }
        __syncthreads();
#pragma unroll
        for (int j = 0; j < 16; ++j) {
            int r = j * 4 + r4;
            w2t[(nt * 64 + r) * 1024 + kt * 64 + c] = __float2bfloat16(tt[c][r]);
        }
    } else if (bid < 512) {                // ---- Pb GEMM (8p x 128c per block)
        __shared__ float pl[8 * 256];
        const int id = bid - 256;
        const int pg = id >> 3;            // 0..31
        const int cgb = (id & 7) * 128;    // col base
#pragma unroll
        for (int i = 0; i < 8; ++i) {
            int idx = t + i * 256;
            pl[idx] = pos_table[pg * 8 * 256 + idx];   // posflat contiguous
        }
        __syncthreads();
        const int prow = t >> 5;
        const int c0 = cgb + (t & 31) * 4;
        f32x4 acc = *(const f32x4*)&b1[c0];
        const float* pr = &pl[prow * 256];
#pragma unroll 4
        for (int k = 0; k < 256; ++k)
            acc += pr[k] * *(const f32x4*)&W1[(16 + k) * 1024 + c0];
        *(f32x4*)&Pb[(pg * 8 + prow) * 1024 + c0] = acc;
    } else if (bid < 516) {                // ---- SUF table
        const int c = (bid - 512) * 256 + t;
        float padv[16];
#pragma unroll
        for (int e = 0; e < 16; ++e) padv[e] = pos_table[4096 * 16 + e];
        float tmp[16];
#pragma unroll
        for (int j = 0; j < 16; ++j) {
            float s = 0.0f;
#pragma unroll
            for (int e = 0; e < 16; ++e)
                s += padv[e] * W1[(16 + 16 * j + e) * 1024 + c];
            tmp[j] = s;
        }
        float run = 0.0f;
        SUF[16 * 1024 + c] = 0.0f;
        for (int m = 15; m >= 0; --m) {
            run += tmp[m];
            SUF[m * 1024 + c] = run;
        }
    } else {                               // ---- scan / rowmap / meta
        __shared__ int sc[NB], sNp[NB];
        if (t < NB) { sNp[t] = (lengths[t] + 15) >> 4; sc[t] = sNp[t]; }
        __syncthreads();
        for (int d = 1; d < NB; d <<= 1) {
            int v = 0;
            if (t < NB && t >= d) v = sc[t - d];
            __syncthreads();
            if (t < NB && t >= d) sc[t] += v;
            __syncthreads();
        }
        if (t < NB) {
            meta[t] = sc[t] - sNp[t];      // exclusive offset
            np_out[t] = (float)sNp[t];
        }
        if (t == 0) meta[NB] = sc[NB - 1]; // Mc
        __syncthreads();
        for (int b = 0; b < NB; ++b) {
            const int off = sc[b] - sNp[b], np = sNp[b];
            for (int p = t; p < np; p += 256)
                rowmap[off + p] = (unsigned short)(b * 256 + p);
        }
    }
}

// ---------------------------------------------------------------- h ----
// h[row] = gelu( vals@W1[:16] + Pb[p] ), 64 rows/block, W1 slice in REGISTERS
// (thread = 8-col group x 16-row quad; W1 loaded once, reused for 16 rows).
__global__ __launch_bounds__(512) void build_h(const float* __restrict__ x,
                                               const int* __restrict__ lengths,
                                               const float* __restrict__ W1,
                                               const float* __restrict__ Pb,
                                               const unsigned short* __restrict__ rowmap,
                                               const int* __restrict__ meta,
                                               hb* __restrict__ h) {
    const int bid = blockIdx.x;            // 0..511, 64 rows each
    const int tid = threadIdx.x;
    const int Mc = meta[NB];
    const int gr0 = bid * 64;
    if (gr0 >= Mc) return;

    __shared__ float vals[64][16];
    __shared__ int rinfo[64];
    if (tid < 64) rinfo[tid] = (gr0 + tid < Mc) ? (int)rowmap[gr0 + tid] : -1;
    __syncthreads();
    for (int i = tid; i < 1024; i += 512) {
        const int row = i >> 4, jj = i & 15;
        const int ri = rinfo[row];
        if (ri >= 0) {
            const int b = ri >> 8, p = ri & 255;
            const int L = lengths[b];
            const int t2 = p * 16 + jj;
            const int idx = (t2 < L) ? t2 : (L - 1);
            vals[row][jj] = x[((long)b * SLEN + idx) * 2];
        }
    }
    __syncthreads();

    const int cg = tid & 127;          // 8-col group, c0 = cg*8
    const int rq = tid >> 7;           // rows rq*16 .. rq*16+15
    const int c0 = cg * 8;

    f32x4 w1r[16][2];                  // 128 VGPRs, statically indexed
#pragma unroll
    for (int j = 0; j < 16; ++j) {
        w1r[j][0] = *(const f32x4*)&W1[j * 1024 + c0];
        w1r[j][1] = *(const f32x4*)&W1[j * 1024 + c0 + 4];
    }

#pragma unroll
    for (int r = 0; r < 16; ++r) {
        const int row = rq * 16 + r;
        const int ri = rinfo[row];
        if (ri < 0) continue;
        const int p = ri & 255;
        f32x4 a0 = *(const f32x4*)&Pb[p * 1024 + c0];
        f32x4 a1 = *(const f32x4*)&Pb[p * 1024 + c0 + 4];
#pragma unroll
        for (int j = 0; j < 16; ++j) {
            const float s = vals[row][j];
            a0 += s * w1r[j][0];
            a1 += s * w1r[j][1];
        }
        bf16x8 o;
#pragma unroll
        for (int e = 0; e < 4; ++e) o[e] = (__bf16)gelu_tanh(a0[e]);
#pragma unroll
        for (int e = 0; e < 4; ++e) o[4 + e] = (__bf16)gelu_tanh(a1[e]);
        *(bf16x8*)(h + (long)(gr0 + row) * 1024 + c0) = o;
    }
}

// boundary rows (one per batch): exact 272-dot with PAD-mixed positions
__global__ __launch_bounds__(256) void boundary_h(const float* __restrict__ x,
                                                  const int* __restrict__ lengths,
                                                  const float* __restrict__ W1,
                                                  const float* __restrict__ b1,
                                                  const float* __restrict__ pos_table,
                                                  const float* __restrict__ SUF,
                                                  const int* __restrict__ meta,
                                                  hb* __restrict__ h) {
    const int b = blockIdx.x;
    const int t = threadIdx.x;
    const int L = lengths[b];
    const int np = (L + 15) >> 4;
    const int p = np - 1;
    const int m = L - p * 16;              // 1..16
    const long gr = meta[b] + p;
    const int c0 = t * 4;

    f32x4 acc = *(const f32x4*)&SUF[m * 1024 + c0];
    acc += *(const f32x4*)&b1[c0];
#pragma unroll
    for (int j = 0; j < 16; ++j) {
        const int tt = p * 16 + j;
        const int idx = (tt < L) ? tt : (L - 1);
        const float v = x[((long)b * SLEN + idx) * 2];
        acc += v * *(const f32x4*)&W1[j * 1024 + c0];
    }
    const int km = m * 16;
    const float* pf = pos_table + p * 256;  // posflat, contiguous
#pragma unroll 4
    for (int k = 0; k < km; ++k)
        acc += pf[k] * *(const f32x4*)&W1[(16 + k) * 1024 + c0];

    hb* hr = h + gr * 1024 + c0;
#pragma unroll
    for (int e = 0; e < 4; ++e) hr[e] = __float2bfloat16(gelu_tanh(acc[e]));
}

// zero all out rows with p >= n_patch(b) — balanced grid-stride (R7-proven)
__global__ __launch_bounds__(256) void zero_fill(const int* __restrict__ lengths,
                                                 float* __restrict__ out) {
    for (int r = blockIdx.x; r < MFULL; r += 512) {
        const int b = r >> 8, p = r & 255;
        const int np = (lengths[b] + 15) >> 4;
        if (p >= np)
            *(f32x4*)(out + (long)r * N_ + threadIdx.x * 4) = (f32x4)0.0f;
    }
}

// ---------------------------------------------------------------- GEMM ----

__device__ __forceinline__ void gl_lds16(const hb* g, hb* l) {
    __builtin_amdgcn_global_load_lds(
        (const __attribute__((address_space(1))) unsigned int*)g,
        (__attribute__((address_space(3))) unsigned int*)l, 16, 0, 0);
}

// out[rowmap[r]] = f32(h_c @ w2t^T + b2), 128x128 tile, BK=64, 4 waves (2x2),
// double-buffered 64 KiB LDS -> 2 blocks/CU (R8-proven structure).
__global__ __launch_bounds__(256, 2) void gemm128(const hb* __restrict__ A,
                                                  const hb* __restrict__ BT,
                                                  const float* __restrict__ bias,
                                                  const unsigned short* __restrict__ rowmap,
                                                  const int* __restrict__ meta,
                                                  float* __restrict__ FOut,
                                                  int K, int nt) {
    __shared__ __align__(16) hb Sh[4][8192];   // A: Sh[0..1], B: Sh[2..3]; 64 KiB

    const int Mc = meta[NB];
    const int nActive = ((Mc + 127) >> 7) * 8;
    const int bid = blockIdx.x;
    if (bid >= nActive) return;
    // bijective chunked XCD swizzle (m204) over the runtime-active grid
    const int q = nActive >> 3, r = nActive & 7;
    const int xcd = bid & 7, idx = bid >> 3;
    const int wg = (xcd < r ? xcd * (q + 1) : r * (q + 1) + (xcd - r) * q) + idx;
    const int bm = wg >> 3;             // bm-major: 8 bn per bm share A-panel on an XCD
    const int bn = wg & 7;

    const int tid = threadIdx.x;
    const int wid = tid >> 6, lane = tid & 63;
    const int wr = wid >> 1, wc = wid & 1;      // 2 x 2 wave grid, 64x64 wave tile
    const int fr = lane & 15, kg = lane >> 4;
    const int swz = (fr & 7) << 4;              // read-side XOR (bytes)

    const long arow0 = (long)bm * 128;
    const int  brow0 = bn * 128;
    const hb* Bbase = BT + (long)brow0 * K;

    // staging: thread -> 16B; pre-swizzled global source, linear LDS dest
    const int srow = tid >> 3;                  // 0..31
    const int sel  = (((tid & 7) << 4) ^ ((srow & 7) << 4)) >> 1;
    const int ldst = tid * 8;

    f32x4 acc[4][4] = {};

    auto stage = [&](int t, int bsel) {
        const int k0 = t << 6;
#pragma unroll
        for (int j = 0; j < 4; ++j) {
            long gr = arow0 + j * 32 + srow;
            if (gr >= Mc) gr = Mc - 1;           // clamp tail rows (dup, discarded)
            gl_lds16(A + gr * K + k0 + sel, &Sh[bsel][j * 2048 + ldst]);
        }
#pragma unroll
        for (int j = 0; j < 4; ++j)
            gl_lds16(Bbase + (long)(j * 32 + srow) * K + k0 + sel,
                     &Sh[2 + bsel][j * 2048 + ldst]);
    };

    stage(0, 0);
    stage(1, 1);
    asm volatile("s_waitcnt vmcnt(8)" ::: "memory");
    asm volatile("s_barrier" ::: "memory");

#define LDA_(dst, Ab, half)                                                  \
    _Pragma("unroll") for (int i = 0; i < 2; ++i)                            \
    _Pragma("unroll") for (int ks = 0; ks < 2; ++ks)                         \
        dst[i][ks] = *(const bf16x8*)((Ab) +                                 \
            (wr * 64 + (half) * 32 + i * 16 + fr) * 128 +                    \
            ((ks * 64 + kg * 16) ^ swz));

#define LDB_(Bb, half)                                                       \
    _Pragma("unroll") for (int jn = 0; jn < 2; ++jn)                         \
    _Pragma("unroll") for (int ks = 0; ks < 2; ++ks)                         \
        Bf[half][jn][ks] = *(const bf16x8*)((Bb) +                           \
            (wc * 64 + (half) * 32 + jn * 16 + fr) * 128 +                   \
            ((ks * 64 + kg * 16) ^ swz));

#define MFMA_QUAD(Aarr, a, b)                                                \
    __builtin_amdgcn_s_setprio(1);                                           \
    _Pragma("unroll") for (int ks = 0; ks < 2; ++ks)                         \
    _Pragma("unroll") for (int i = 0; i < 2; ++i)                            \
    _Pragma("unroll") for (int jn = 0; jn < 2; ++jn)                         \
        acc[(a) * 2 + i][(b) * 2 + jn] =                                     \
            __builtin_amdgcn_mfma_f32_16x16x32_bf16(                         \
                Aarr[i][ks], Bf[b][jn][ks], acc[(a) * 2 + i][(b) * 2 + jn],  \
                0, 0, 0);                                                    \
    __builtin_amdgcn_s_setprio(0);

    for (int t = 0; t < nt; ++t) {
        const char* Ab = (const char*)(&Sh[t & 1][0]);
        const char* Bb = (const char*)(&Sh[2 + (t & 1)][0]);
        bf16x8 A0[2][2], A1[2][2], Bf[2][2][2];

        LDB_(Bb, 0)
        LDA_(A0, Ab, 0)
        MFMA_QUAD(A0, 0, 0)
        LDB_(Bb, 1)
        MFMA_QUAD(A0, 0, 1)
        LDA_(A1, Ab, 1)
        MFMA_QUAD(A1, 1, 1)
        asm volatile("s_waitcnt lgkmcnt(0)" ::: "memory");
        asm volatile("s_barrier" ::: "memory");
        if (t + 2 < nt) stage(t + 2, t & 1);
        MFMA_QUAD(A1, 1, 0)
        if (t + 1 < nt) {
            if (t + 2 < nt) {
                asm volatile("s_waitcnt vmcnt(8)" ::: "memory");
            } else {
                asm volatile("s_waitcnt vmcnt(0)" ::: "memory");
            }
            asm volatile("s_barrier" ::: "memory");
        }
    }

    // ---- LDS-staged epilogue, rowmap scatter ----
    const int rbase = wr * 64 + kg * 4;
    const int cbase = wc * 64 + fr;
    float bvv[4];
#pragma unroll
    for (int ni = 0; ni < 4; ++ni) bvv[ni] = bias[bn * 128 + cbase + ni * 16];

    float* Cf = (float*)Sh;                // 128 x 128 f32 tile (64 KiB)
#pragma unroll
    for (int ni = 0; ni < 4; ++ni) {
        const int col = cbase + ni * 16;
#pragma unroll
        for (int mi = 0; mi < 4; ++mi)
#pragma unroll
            for (int r2 = 0; r2 < 4; ++r2)
                Cf[(rbase + mi * 16 + r2) * 128 + col] = acc[mi][ni][r2] + bvv[ni];
    }
    __syncthreads();
#pragma unroll
    for (int c = 0; c < 16; ++c) {
        const int e = (c * 256 + tid) * 4;
        const int row = e >> 7, col = e & 127;
        const long cidx = arow0 + row;
        if (cidx < Mc) {
            f32x4 v = *(const f32x4*)(Cf + e);
            *(f32x4*)(FOut + (long)rowmap[cidx] * N_ + bn * 128 + col) = v;
        }
    }
}

// -------------------------------------------------------------- launch ----

extern "C" void kernel_launch(void* const* d_in, const int* in_sizes, int n_in,
                              void* d_out, int out_size, void* d_ws, size_t ws_size,
                              hipStream_t stream) {
    const float* x         = (const float*)d_in[0];
    const int*   lengths   = (const int*)d_in[1];
    const float* pos_table = (const float*)d_in[2];
    const float* W1        = (const float*)d_in[3];
    const float* b1        = (const float*)d_in[4];
    const float* W2        = (const float*)d_in[5];
    const float* b2        = (const float*)d_in[6];
    float* out = (float*)d_out;

    char* ws = (char*)d_ws;
    hb* w2t                = (hb*)(ws);                        //  2,097,152 B
    hb* h                  = (hb*)(ws + 2097152);              // 67,108,864 B
    float* Pb              = (float*)(ws + 69206016);          //  1,048,576 B
    float* SUF             = (float*)(ws + 70254592);          //     69,632 B
    unsigned short* rowmap = (unsigned short*)(ws + 70324224); //     65,536 B
    int* meta              = (int*)(ws + 70389760);            //        516 B

    hipLaunchKernelGGL(prep_all, dim3(517), dim3(256), 0, stream,
                       W1, b1, W2, pos_table, lengths, w2t, Pb, SUF, rowmap, meta,
                       out + (long)MFULL * N_);
    hipLaunchKernelGGL(zero_fill, dim3(512), dim3(256), 0, stream, lengths, out);
    hipLaunchKernelGGL(build_h, dim3(512), dim3(512), 0, stream,
                       x, lengths, W1, Pb, rowmap, meta, h);
    hipLaunchKernelGGL(boundary_h, dim3(NB), dim3(256), 0, stream,
                       x, lengths, W1, b1, pos_table, SUF, meta, h);
    hipLaunchKernelGGL(gemm128, dim3(2048), dim3(256), 0, stream,
                       h, w2t, b2, rowmap, meta, out, 1024, 16);
}

// Round 14
// 98.002 us; speedup vs baseline: 2.2429x; 1.7707x over previous
//
#include <hip/hip_runtime.h>
#include <hip/hip_bf16.h>
#include <math.h>

// Problem constants
#define NB     128          // batches
#define SLEN   4096
#define HID_   1024
#define INDIM_ 272
#define KPAD_  320          // 272 padded to 5*64
#define MFULL  32768
#define N_     1024

typedef __bf16 bf16x8 __attribute__((ext_vector_type(8)));
typedef float  f32x4  __attribute__((ext_vector_type(4)));
typedef float  f32x2  __attribute__((ext_vector_type(2)));
typedef __hip_bfloat16 hb;

// ---------------------------------------------------------------- prep ----

// kt<5: W1 (272x1024) f32 -> w1t (1024x320) bf16^T zero-padded
// kt>=5: W2 (1024x1024) f32 -> w2t (1024x1024) bf16^T
__global__ void prep_w(const float* __restrict__ W1, const float* __restrict__ W2,
                       hb* __restrict__ w1t, hb* __restrict__ w2t) {
    __shared__ float tt[64][65];
    const int kt = blockIdx.x;           // 0..20
    const int nt = blockIdx.y;           // 0..15
    const int c = threadIdx.x & 63, r4 = threadIdx.x >> 6;
    if (kt < 5) {
#pragma unroll
        for (int j = 0; j < 16; ++j) {
            int r = j * 4 + r4;
            int k = kt * 64 + r;
            tt[r][c] = (k < INDIM_) ? W1[k * 1024 + nt * 64 + c] : 0.0f;
        }
        __syncthreads();
#pragma unroll
        for (int j = 0; j < 16; ++j) {
            int r = j * 4 + r4;
            w1t[(nt * 64 + r) * KPAD_ + kt * 64 + c] = __float2bfloat16(tt[c][r]);
        }
    } else {
        const int kw = kt - 5;
#pragma unroll
        for (int j = 0; j < 16; ++j) {
            int r = j * 4 + r4;
            tt[r][c] = W2[(kw * 64 + r) * 1024 + nt * 64 + c];
        }
        __syncthreads();
#pragma unroll
        for (int j = 0; j < 16; ++j) {
            int r = j * 4 + r4;
            w2t[(nt * 64 + r) * 1024 + kw * 64 + c] = __float2bfloat16(tt[c][r]);
        }
    }
}

// Per-(batch, chunk-of-64-patches): np scan (redundant), n_patch output + Mc
// (block 0,0), rowmap + compact feat rows for this chunk, fused balanced
// zero-fill stripe of invalid out rows.
__global__ __launch_bounds__(512) void build_feat_c(const float* __restrict__ x,
                                                    const int* __restrict__ lengths,
                                                    const float* __restrict__ pos_table,
                                                    hb* __restrict__ feat,
                                                    unsigned short* __restrict__ rowmap,
                                                    int* __restrict__ mc,
                                                    float* __restrict__ np_out,
                                                    float* __restrict__ out) {
    __shared__ int scan[NB];
    const int b = blockIdx.x, t = threadIdx.x;
    const int chunk = blockIdx.y;             // 0..3
    if (t < NB) scan[t] = (lengths[t] + 15) >> 4;
    __syncthreads();
    for (int d = 1; d < NB; d <<= 1) {        // Hillis-Steele inclusive scan
        int v = 0;
        if (t < NB && t >= d) v = scan[t - d];
        __syncthreads();
        if (t < NB && t >= d) scan[t] += v;
        __syncthreads();
    }
    const int L = lengths[b];
    const int np = (L + 15) >> 4;
    const int off = scan[b] - np;
    if (b == 0 && chunk == 0) {
        if (t < NB) np_out[t] = (float)((lengths[t] + 15) >> 4);
        if (t == 0) *mc = scan[NB - 1];
    }

    // balanced zero-fill stripe (identical distribution to R7's standalone kernel)
    const int z = b * 4 + chunk;              // 0..511
    for (int r = z; r < MFULL; r += 512) {
        const int bb = r >> 8, p = r & 255;
        const int npb = (lengths[bb] + 15) >> 4;
        if (p >= npb)
            *(f32x2*)(out + (long)r * N_ + t * 2) = (f32x2)0.0f;
    }

    const int p0 = chunk * 64;
    const int p1 = min(np, p0 + 64);
    if (p0 >= p1) return;
    const int cnt = p1 - p0;

    for (int p = p0 + t; p < p1; p += 512)
        rowmap[off + p] = (unsigned short)(b * 256 + p);

    const float* xb = x + (long)b * SLEN * 2;
    const int total = cnt * 40;
    for (int c = t; c < total; c += 512) {
        const int pr = c / 40;
        const int p = p0 + pr;
        const int j = c - pr * 40;
        const int col = j * 8;
        bf16x8 v;
        if (j < 2) {
#pragma unroll
            for (int e = 0; e < 8; ++e) {
                int tt2 = p * 16 + j * 8 + e;
                int idx = (tt2 < L) ? tt2 : (L - 1);
                v[e] = (__bf16)xb[(long)idx * 2];
            }
        } else if (col < INDIM_) {
            const int q = col - 16;
            const int tt2 = p * 16 + (q >> 4);
            const int pt = (tt2 < L) ? tt2 : SLEN;
            const float* src = pos_table + pt * 16 + (q & 15);
#pragma unroll
            for (int e = 0; e < 8; ++e) v[e] = (__bf16)src[e];
        } else {
            v = (bf16x8)0;
        }
        *(bf16x8*)(feat + (long)(off + p) * KPAD_ + col) = v;
    }
}

// ---------------------------------------------------------------- GEMM ----

__device__ __forceinline__ void gl_lds16(const hb* g, hb* l) {
    __builtin_amdgcn_global_load_lds(
        (const __attribute__((address_space(1))) unsigned int*)g,
        (__attribute__((address_space(3))) unsigned int*)l, 16, 0, 0);
}

__device__ __forceinline__ float gelu_tanh(float v) {
    float u = 1.5957691216f * v * (1.0f + 0.044715f * v * v);
    float e = __expf(u);
    float th = (e - 1.0f) / (e + 1.0f);
    return 0.5f * v * (1.0f + th);
}

// C(Mc x 1024) = A(Mc x K) @ BT(1024 x K)^T, compact rows.
// 256x256 tile, BK=64, 8 waves (2x4), double-buffered LDS (R5/R7-proven loop).
// Runtime-bijective XCD swizzle over nActive = ceil(Mc/256)*4 blocks.
// MODE 0: HOut = bf16(gelu(C+bias)) compact;  MODE 1: FOut[rowmap[r]] = f32(C+bias)
template <int MODE>
__global__ __launch_bounds__(512, 2) void gemm256(const hb* __restrict__ A,
                                                  const hb* __restrict__ BT,
                                                  const float* __restrict__ bias,
                                                  const unsigned short* __restrict__ rowmap,
                                                  const int* __restrict__ mc,
                                                  hb* __restrict__ HOut,
                                                  float* __restrict__ FOut,
                                                  int K, int nt) {
    __shared__ __align__(16) hb Sh[4][16384];   // A: Sh[0..1], B: Sh[2..3]; 128 KiB

    const int Mc = *mc;
    const int activeBm = (Mc + 255) >> 8;
    const int nActive = activeBm * 4;
    const int bid = blockIdx.x;
    if (bid >= nActive) return;
    // bijective chunked XCD swizzle (m204) over the runtime-active grid
    const int q = nActive >> 3, r = nActive & 7;
    const int xcd = bid & 7, idx = bid >> 3;
    const int wg = (xcd < r ? xcd * (q + 1) : r * (q + 1) + (xcd - r) * q) + idx;
    const int bm = wg >> 2;             // bm-major: 4 bn per bm share A-panel on an XCD
    const int bn = wg & 3;

    const int tid = threadIdx.x;
    const int wid = tid >> 6, lane = tid & 63;
    const int wr = wid >> 2, wc = wid & 3;      // 2 x 4 wave grid
    const int fr = lane & 15, kg = lane >> 4;
    const int swz = (fr & 7) << 4;              // read-side XOR (bytes)

    const long arow0 = (long)bm * 256;
    const int  brow0 = bn * 256;
    const hb* Bbase = BT + (long)brow0 * K;

    // staging: thread -> 16B; pre-swizzled global source, linear LDS dest
    const int srow = tid >> 3;
    const int sel  = (((tid & 7) << 4) ^ ((srow & 7) << 4)) >> 1;
    const int ldst = tid * 8;

    f32x4 acc[8][4] = {};

    auto stage = [&](int t, int bsel) {
        const int k0 = t << 6;
#pragma unroll
        for (int j = 0; j < 4; ++j) {
            long gr = arow0 + j * 64 + srow;
            if (gr >= Mc) gr = Mc - 1;           // clamp tail rows (dup, discarded)
            gl_lds16(A + gr * K + k0 + sel, &Sh[bsel][j * 4096 + ldst]);
        }
#pragma unroll
        for (int j = 0; j < 4; ++j)
            gl_lds16(Bbase + (long)(j * 64 + srow) * K + k0 + sel,
                     &Sh[2 + bsel][j * 4096 + ldst]);
    };

    stage(0, 0);
    stage(1, 1);
    asm volatile("s_waitcnt vmcnt(8)" ::: "memory");
    asm volatile("s_barrier" ::: "memory");

#define LDA_(dst, Ab, half)                                                  \
    _Pragma("unroll") for (int i = 0; i < 4; ++i)                            \
    _Pragma("unroll") for (int ks = 0; ks < 2; ++ks)                         \
        dst[i][ks] = *(const bf16x8*)((Ab) +                                 \
            (wr * 128 + (half) * 64 + i * 16 + fr) * 128 +                   \
            ((ks * 64 + kg * 16) ^ swz));

#define LDB_(Bb, half)                                                       \
    _Pragma("unroll") for (int jn = 0; jn < 2; ++jn)                         \
    _Pragma("unroll") for (int ks = 0; ks < 2; ++ks)                         \
        Bf[half][jn][ks] = *(const bf16x8*)((Bb) +                           \
            (wc * 64 + (half) * 32 + jn * 16 + fr) * 128 +                   \
            ((ks * 64 + kg * 16) ^ swz));

#define MFMA_QUAD(Aarr, a, b)                                                \
    __builtin_amdgcn_s_setprio(1);                                           \
    _Pragma("unroll") for (int ks = 0; ks < 2; ++ks)                         \
    _Pragma("unroll") for (int i = 0; i < 4; ++i)                            \
    _Pragma("unroll") for (int jn = 0; jn < 2; ++jn)                         \
        acc[(a) * 4 + i][(b) * 2 + jn] =                                     \
            __builtin_amdgcn_mfma_f32_16x16x32_bf16(                         \
                Aarr[i][ks], Bf[b][jn][ks], acc[(a) * 4 + i][(b) * 2 + jn],  \
                0, 0, 0);                                                    \
    __builtin_amdgcn_s_setprio(0);

    for (int t = 0; t < nt; ++t) {
        const char* Ab = (const char*)(&Sh[t & 1][0]);
        const char* Bb = (const char*)(&Sh[2 + (t & 1)][0]);
        bf16x8 A0[4][2], A1[4][2], Bf[2][2][2];

        LDB_(Bb, 0)
        LDA_(A0, Ab, 0)
        MFMA_QUAD(A0, 0, 0)
        LDB_(Bb, 1)
        MFMA_QUAD(A0, 0, 1)
        LDA_(A1, Ab, 1)
        MFMA_QUAD(A1, 1, 1)
        asm volatile("s_waitcnt lgkmcnt(0)" ::: "memory");
        asm volatile("s_barrier" ::: "memory");
        if (t + 2 < nt) stage(t + 2, t & 1);
        MFMA_QUAD(A1, 1, 0)
        if (t + 1 < nt) {
            if (t + 2 < nt) {
                asm volatile("s_waitcnt vmcnt(8)" ::: "memory");
            } else {
                asm volatile("s_waitcnt vmcnt(0)" ::: "memory");
            }
            asm volatile("s_barrier" ::: "memory");
        }
    }

    // ---- LDS-staged epilogue ----
    const int rbase = wr * 128 + kg * 4;
    const int cbase = wc * 64 + fr;
    float bvv[4];
#pragma unroll
    for (int ni = 0; ni < 4; ++ni) bvv[ni] = bias[bn * 256 + cbase + ni * 16];

    if (MODE == 0) {
        hb* Cs = (hb*)Sh;                      // 256 x 256 bf16 tile
#pragma unroll
        for (int ni = 0; ni < 4; ++ni) {
            const int col = cbase + ni * 16;
#pragma unroll
            for (int mi = 0; mi < 8; ++mi)
#pragma unroll
                for (int r2 = 0; r2 < 4; ++r2) {
                    float v = acc[mi][ni][r2] + bvv[ni];
                    Cs[(rbase + mi * 16 + r2) * 256 + col] = __float2bfloat16(gelu_tanh(v));
                }
        }
        __syncthreads();
        const hb* Cl = (const hb*)Sh;
#pragma unroll
        for (int c = 0; c < 16; ++c) {
            const int e = (c * 512 + tid) * 8;
            const int row = e >> 8, col = e & 255;
            bf16x8 v = *(const bf16x8*)(Cl + e);
            *(bf16x8*)(HOut + (arow0 + row) * N_ + bn * 256 + col) = v;
        }
    } else {
        float* Cf = (float*)Sh;                // 256 x 128 f32 per half
#pragma unroll
        for (int half = 0; half < 2; ++half) {
            if (half) __syncthreads();
            if ((wc >> 1) == half) {
#pragma unroll
                for (int ni = 0; ni < 4; ++ni) {
                    const int col = cbase + ni * 16 - half * 128;
#pragma unroll
                    for (int mi = 0; mi < 8; ++mi)
#pragma unroll
                        for (int r2 = 0; r2 < 4; ++r2)
                            Cf[(rbase + mi * 16 + r2) * 128 + col] =
                                acc[mi][ni][r2] + bvv[ni];
                }
            }
            __syncthreads();
#pragma unroll
            for (int c = 0; c < 16; ++c) {
                const int e = (c * 512 + tid) * 4;
                const int row = e >> 7, col = e & 127;
                const long cidx = arow0 + row;
                if (cidx < Mc) {
                    f32x4 v = *(const f32x4*)(Cf + e);
                    *(f32x4*)(FOut + (long)rowmap[cidx] * N_ + bn * 256 + half * 128 + col) = v;
                }
            }
        }
    }
}

// -------------------------------------------------------------- launch ----

extern "C" void kernel_launch(void* const* d_in, const int* in_sizes, int n_in,
                              void* d_out, int out_size, void* d_ws, size_t ws_size,
                              hipStream_t stream) {
    const float* x         = (const float*)d_in[0];
    const int*   lengths   = (const int*)d_in[1];
    const float* pos_table = (const float*)d_in[2];
    const float* W1        = (const float*)d_in[3];
    const float* b1        = (const float*)d_in[4];
    const float* W2        = (const float*)d_in[5];
    const float* b2        = (const float*)d_in[6];
    float* out = (float*)d_out;

    char* ws = (char*)d_ws;
    hb* w1t                = (hb*)(ws);                        //    655,360 B
    hb* w2t                = (hb*)(ws + 655360);               //  2,097,152 B
    hb* feat               = (hb*)(ws + 2752512);              // 20,971,520 B max
    hb* h                  = (hb*)(ws + 23724032);             // 67,108,864 B max
    unsigned short* rowmap = (unsigned short*)(ws + 90832896); //     65,536 B
    int* mc                = (int*)(ws + 90898432);            //          4 B

    hipLaunchKernelGGL(prep_w, dim3(21, 16), dim3(256), 0, stream, W1, W2, w1t, w2t);
    hipLaunchKernelGGL(build_feat_c, dim3(NB, 4), dim3(512), 0, stream,
                       x, lengths, pos_table, feat, rowmap, mc,
                       out + (long)MFULL * N_, out);

    // gemm grids: nActive <= 260; excess blocks exit immediately
    hipLaunchKernelGGL((gemm256<0>), dim3(512), dim3(512), 0, stream,
                       feat, w1t, b1, rowmap, mc, h, nullptr, KPAD_, KPAD_ / 64);
    hipLaunchKernelGGL((gemm256<1>), dim3(512), dim3(512), 0, stream,
                       h, w2t, b2, rowmap, mc, nullptr, out, HID_, HID_ / 64);
}